// Round 1
// baseline (1064.421 us; speedup 1.0000x reference)
//
#include <hip/hip_runtime.h>
#include <hip/hip_bf16.h>

constexpr int HID = 512;
constexpr int NH  = 8;
constexpr int HD  = 64;
constexpr int NB  = 2;
constexpr int SEQ = 2048;
constexpr int M   = NB * SEQ;        // 4096 token rows
constexpr int NROWS = NB * NH * SEQ; // 32768 attention rows
constexpr int SKB = SEQ / 64;        // 32 sk blocks

typedef __attribute__((ext_vector_type(8))) short bf16x8;
typedef __attribute__((ext_vector_type(4))) float f32x4;

__device__ __forceinline__ unsigned short f2bf(float x){
    union { float f; unsigned u; } v; v.f = x;
    return (unsigned short)((v.u + 0x7fffu + ((v.u >> 16) & 1u)) >> 16);
}
__device__ __forceinline__ float bf2f(unsigned short h){
    union { unsigned u; float f; } v; v.u = (unsigned)h << 16;
    return v.f;
}

// ---------- input convert / split (hi+lo bf16 decomposition of fp32) ----------
__global__ void cvt_split(const float* __restrict__ x, unsigned short* __restrict__ hi,
                          unsigned short* __restrict__ lo, int n){
    int i = blockIdx.x * 256 + threadIdx.x;
    if (i >= n) return;
    float f = x[i];
    unsigned short h = f2bf(f);
    hi[i] = h;
    if (lo) lo[i] = f2bf(f - bf2f(h));
}

// ---------- weight transpose (+optional split): wt[n][k] = w[k][n] ----------
__global__ void cvt_w(const float* __restrict__ w, unsigned short* __restrict__ hi,
                      unsigned short* __restrict__ lo){
    __shared__ float t[32][33];
    int n0 = blockIdx.x * 32, k0 = blockIdx.y * 32;
    int tx = threadIdx.x, ty = threadIdx.y;
    for (int r = ty; r < 32; r += 8)
        t[r][tx] = w[(size_t)(k0 + r) * HID + n0 + tx];
    __syncthreads();
    for (int r = ty; r < 32; r += 8){
        float f = t[tx][r];                       // element (k=k0+tx, n=n0+r)
        unsigned short hb = f2bf(f);
        size_t o = (size_t)(n0 + r) * HID + k0 + tx;
        hi[o] = hb;
        if (lo) lo[o] = f2bf(f - bf2f(hb));
    }
}

// ---------- projection GEMM: Y[4096,512] = X @ W + b, MFMA 16x16x32 bf16 ----------
// SPLIT=1: compensated (hi/lo) inputs and split outputs (Q/K path).
// VOUT=1: write V output transposed [b,h,d,s] (single bf16).
template<int SPLIT, int VOUT>
__global__ __launch_bounds__(256) void proj_gemm(
    const unsigned short* __restrict__ Ahi, const unsigned short* __restrict__ Alo,
    const unsigned short* __restrict__ Bhi, const unsigned short* __restrict__ Blo,
    const float* __restrict__ bias,
    unsigned short* __restrict__ Ohi, unsigned short* __restrict__ Olo)
{
    __shared__ __align__(16) unsigned short As[SPLIT + 1][64][40]; // +8 pad: 2-way LDS conflicts only
    __shared__ __align__(16) unsigned short Bs[SPLIT + 1][64][40];
    const int m0 = blockIdx.y * 64, n0 = blockIdx.x * 64;
    const int tid = threadIdx.x, w = tid >> 6, lane = tid & 63;
    const int wm = (w >> 1) * 32, wn = (w & 1) * 32;
    const int srow = tid >> 2, sch = (tid & 3) * 8;
    f32x4 acc[2][2] = {};
    for (int k0 = 0; k0 < HID; k0 += 32){
        *(bf16x8*)&As[0][srow][sch] = *(const bf16x8*)(Ahi + (size_t)(m0 + srow) * HID + k0 + sch);
        *(bf16x8*)&Bs[0][srow][sch] = *(const bf16x8*)(Bhi + (size_t)(n0 + srow) * HID + k0 + sch);
        if (SPLIT){
            *(bf16x8*)&As[1][srow][sch] = *(const bf16x8*)(Alo + (size_t)(m0 + srow) * HID + k0 + sch);
            *(bf16x8*)&Bs[1][srow][sch] = *(const bf16x8*)(Blo + (size_t)(n0 + srow) * HID + k0 + sch);
        }
        __syncthreads();
        const int fr = lane & 15, kc = (lane >> 4) * 8;
        #pragma unroll
        for (int fm = 0; fm < 2; fm++)
        #pragma unroll
        for (int fn = 0; fn < 2; fn++){
            bf16x8 aH = *(bf16x8*)&As[0][wm + fm*16 + fr][kc];
            bf16x8 bH = *(bf16x8*)&Bs[0][wn + fn*16 + fr][kc];
            acc[fm][fn] = __builtin_amdgcn_mfma_f32_16x16x32_bf16(aH, bH, acc[fm][fn], 0, 0, 0);
            if (SPLIT){
                bf16x8 aL = *(bf16x8*)&As[1][wm + fm*16 + fr][kc];
                bf16x8 bL = *(bf16x8*)&Bs[1][wn + fn*16 + fr][kc];
                acc[fm][fn] = __builtin_amdgcn_mfma_f32_16x16x32_bf16(aL, bH, acc[fm][fn], 0, 0, 0);
                acc[fm][fn] = __builtin_amdgcn_mfma_f32_16x16x32_bf16(aH, bL, acc[fm][fn], 0, 0, 0);
            }
        }
        __syncthreads();
    }
    #pragma unroll
    for (int fm = 0; fm < 2; fm++)
    #pragma unroll
    for (int fn = 0; fn < 2; fn++){
        int col = n0 + wn + fn*16 + (lane & 15);   // C/D: col = lane&15 (m89/m91)
        int rb  = m0 + wm + fm*16 + (lane >> 4) * 4;
        float bv = bias[col];
        int h = col >> 6, d = col & 63;
        #pragma unroll
        for (int e = 0; e < 4; e++){
            int m = rb + e;
            int b = m >> 11, s = m & (SEQ - 1);
            float y = acc[fm][fn][e] + bv;
            if (VOUT){
                Ohi[((size_t)((b * NH + h) * HD + d)) * SEQ + s] = f2bf(y);
            } else {
                size_t o = ((size_t)((b * NH + h) * SEQ + s)) * HD + d;
                unsigned short hb = f2bf(y);
                Ohi[o] = hb;
                if (SPLIT) Olo[o] = f2bf(y - bf2f(hb));
            }
        }
    }
}

// ---------- scores: p_unnorm = exp(QK^T*scale + bias, masked), + row partial sums ----------
__global__ __launch_bounds__(256) void scores_kernel(
    const unsigned short* __restrict__ qh_hi, const unsigned short* __restrict__ qh_lo,
    const unsigned short* __restrict__ kh_hi, const unsigned short* __restrict__ kh_lo,
    const float* __restrict__ attn_bias, const int* __restrict__ attn_mask,
    float* __restrict__ scores, float* __restrict__ partials)
{
    __shared__ __align__(16) unsigned short Aq[2][64][72];
    __shared__ __align__(16) unsigned short Bk[2][64][72];
    __shared__ float Pt[64][68];
    __shared__ float rs[64][4];
    const int sk0 = blockIdx.x * 64, sq0 = blockIdx.y * 64, bh = blockIdx.z;
    const int b = bh >> 3;
    const int tid = threadIdx.x, w = tid >> 6, lane = tid & 63;
    const int wm = (w >> 1) * 32, wn = (w & 1) * 32;

    for (int idx = tid; idx < 512; idx += 256){
        int row = idx >> 3, ch = (idx & 7) * 8;
        size_t qo = ((size_t)bh * SEQ + sq0 + row) * HD + ch;
        size_t ko = ((size_t)bh * SEQ + sk0 + row) * HD + ch;
        *(bf16x8*)&Aq[0][row][ch] = *(const bf16x8*)(qh_hi + qo);
        *(bf16x8*)&Aq[1][row][ch] = *(const bf16x8*)(qh_lo + qo);
        *(bf16x8*)&Bk[0][row][ch] = *(const bf16x8*)(kh_hi + ko);
        *(bf16x8*)&Bk[1][row][ch] = *(const bf16x8*)(kh_lo + ko);
    }
    __syncthreads();
    f32x4 acc[2][2] = {};
    const int fr = lane & 15, kc8 = (lane >> 4) * 8;
    #pragma unroll
    for (int ks = 0; ks < 2; ks++){
        int kc = ks * 32 + kc8;
        #pragma unroll
        for (int fm = 0; fm < 2; fm++)
        #pragma unroll
        for (int fn = 0; fn < 2; fn++){
            bf16x8 aH = *(bf16x8*)&Aq[0][wm + fm*16 + fr][kc];
            bf16x8 aL = *(bf16x8*)&Aq[1][wm + fm*16 + fr][kc];
            bf16x8 bH = *(bf16x8*)&Bk[0][wn + fn*16 + fr][kc];
            bf16x8 bL = *(bf16x8*)&Bk[1][wn + fn*16 + fr][kc];
            acc[fm][fn] = __builtin_amdgcn_mfma_f32_16x16x32_bf16(aH, bH, acc[fm][fn], 0, 0, 0);
            acc[fm][fn] = __builtin_amdgcn_mfma_f32_16x16x32_bf16(aL, bH, acc[fm][fn], 0, 0, 0);
            acc[fm][fn] = __builtin_amdgcn_mfma_f32_16x16x32_bf16(aH, bL, acc[fm][fn], 0, 0, 0);
        }
    }
    #pragma unroll
    for (int fm = 0; fm < 2; fm++)
    #pragma unroll
    for (int fn = 0; fn < 2; fn++){
        int c  = wn + fn*16 + (lane & 15);
        int rb = wm + fm*16 + (lane >> 4) * 4;
        #pragma unroll
        for (int e = 0; e < 4; e++){
            int r = rb + e;
            int sq = sq0 + r, sk = sk0 + c;
            float x = acc[fm][fn][e] * 0.125f + attn_bias[((size_t)bh * SEQ + sq) * SEQ + sk];
            int mk = attn_mask[((size_t)(b * SEQ + sq)) * SEQ + sk];
            float p = mk ? 0.0f : __expf(x);   // no max-subtraction needed: |x| <~ 10
            scores[((size_t)bh * SEQ + sq) * SEQ + sk] = p;
            Pt[r][c] = p;
        }
    }
    __syncthreads();
    {
        int r = tid >> 2, qq = tid & 3;
        float s = 0.f;
        #pragma unroll
        for (int j = 0; j < 16; j++) s += Pt[r][qq * 16 + j];
        rs[r][qq] = s;
    }
    __syncthreads();
    if (tid < 64){
        float s = rs[tid][0] + rs[tid][1] + rs[tid][2] + rs[tid][3];
        partials[(size_t)blockIdx.x * NROWS + (size_t)bh * SEQ + sq0 + tid] = s;
    }
}

// ---------- reduce partial sums -> 1/l ----------
__global__ void rowsum_inv(const float* __restrict__ partials, float* __restrict__ invl){
    int r = blockIdx.x * 256 + threadIdx.x;
    float s = 0.f;
    for (int j = 0; j < SKB; j++) s += partials[(size_t)j * NROWS + r];
    invl[r] = 1.0f / s;
}

// ---------- normalize scores in place + ctx = P @ V ----------
__global__ __launch_bounds__(256) void pv_kernel(
    float* __restrict__ scores, const float* __restrict__ invl,
    const unsigned short* __restrict__ vh_t, unsigned short* __restrict__ ctx)
{
    __shared__ __align__(16) unsigned short Ap[64][72];
    __shared__ __align__(16) unsigned short Bv[64][72];
    __shared__ float il[64];
    const int sq0 = blockIdx.x * 64, bh = blockIdx.y;
    const int tid = threadIdx.x, w = tid >> 6, lane = tid & 63;
    const int wm = (w >> 1) * 32, wn = (w & 1) * 32;
    if (tid < 64) il[tid] = invl[(size_t)bh * SEQ + sq0 + tid];
    __syncthreads();
    f32x4 acc[2][2] = {};
    for (int sk0 = 0; sk0 < SEQ; sk0 += 64){
        for (int idx = tid; idx < 1024; idx += 256){
            int row = idx >> 4, c4 = (idx & 15) * 4;
            size_t o = ((size_t)bh * SEQ + sq0 + row) * SEQ + sk0 + c4;
            float4 pv = *(float4*)(scores + o);
            float sc = il[row];
            pv.x *= sc; pv.y *= sc; pv.z *= sc; pv.w *= sc;
            *(float4*)(scores + o) = pv;       // final normalized scores output
            ushort4 u; u.x = f2bf(pv.x); u.y = f2bf(pv.y); u.z = f2bf(pv.z); u.w = f2bf(pv.w);
            *(ushort4*)&Ap[row][c4] = u;
        }
        for (int idx = tid; idx < 512; idx += 256){
            int row = idx >> 3, ch = (idx & 7) * 8;
            *(bf16x8*)&Bv[row][ch] = *(const bf16x8*)(vh_t + ((size_t)bh * HD + row) * SEQ + sk0 + ch);
        }
        __syncthreads();
        const int fr = lane & 15, kc8 = (lane >> 4) * 8;
        #pragma unroll
        for (int ks = 0; ks < 2; ks++){
            int kc = ks * 32 + kc8;
            #pragma unroll
            for (int fm = 0; fm < 2; fm++)
            #pragma unroll
            for (int fn = 0; fn < 2; fn++){
                bf16x8 a  = *(bf16x8*)&Ap[wm + fm*16 + fr][kc];
                bf16x8 bb = *(bf16x8*)&Bv[wn + fn*16 + fr][kc];
                acc[fm][fn] = __builtin_amdgcn_mfma_f32_16x16x32_bf16(a, bb, acc[fm][fn], 0, 0, 0);
            }
        }
        __syncthreads();
    }
    // ctx tile -> LDS bounce -> coalesced bf16 write at [b,s,h*64+d]
    #pragma unroll
    for (int fm = 0; fm < 2; fm++)
    #pragma unroll
    for (int fn = 0; fn < 2; fn++){
        int c  = wn + fn*16 + (lane & 15);
        int rb = wm + fm*16 + (lane >> 4) * 4;
        #pragma unroll
        for (int e = 0; e < 4; e++)
            Ap[rb + e][c] = f2bf(acc[fm][fn][e]);
    }
    __syncthreads();
    const int b = bh >> 3, h = bh & 7;
    for (int idx = tid; idx < 512; idx += 256){
        int row = idx >> 3, ch = (idx & 7) * 8;
        size_t o = ((size_t)(b * SEQ + sq0 + row)) * HID + h * HD + ch;
        *(bf16x8*)(ctx + o) = *(bf16x8*)&Ap[row][ch];
    }
}

// ---------- out = ctx @ Wo + bo (fp32 out) ----------
__global__ __launch_bounds__(256) void out_gemm(
    const unsigned short* __restrict__ A, const unsigned short* __restrict__ Bt,
    const float* __restrict__ bias, float* __restrict__ out)
{
    __shared__ __align__(16) unsigned short As[64][40];
    __shared__ __align__(16) unsigned short Bs[64][40];
    const int m0 = blockIdx.y * 64, n0 = blockIdx.x * 64;
    const int tid = threadIdx.x, w = tid >> 6, lane = tid & 63;
    const int wm = (w >> 1) * 32, wn = (w & 1) * 32;
    const int srow = tid >> 2, sch = (tid & 3) * 8;
    f32x4 acc[2][2] = {};
    for (int k0 = 0; k0 < HID; k0 += 32){
        *(bf16x8*)&As[srow][sch] = *(const bf16x8*)(A  + (size_t)(m0 + srow) * HID + k0 + sch);
        *(bf16x8*)&Bs[srow][sch] = *(const bf16x8*)(Bt + (size_t)(n0 + srow) * HID + k0 + sch);
        __syncthreads();
        const int fr = lane & 15, kc = (lane >> 4) * 8;
        #pragma unroll
        for (int fm = 0; fm < 2; fm++)
        #pragma unroll
        for (int fn = 0; fn < 2; fn++){
            bf16x8 a = *(bf16x8*)&As[wm + fm*16 + fr][kc];
            bf16x8 b = *(bf16x8*)&Bs[wn + fn*16 + fr][kc];
            acc[fm][fn] = __builtin_amdgcn_mfma_f32_16x16x32_bf16(a, b, acc[fm][fn], 0, 0, 0);
        }
        __syncthreads();
    }
    #pragma unroll
    for (int fm = 0; fm < 2; fm++)
    #pragma unroll
    for (int fn = 0; fn < 2; fn++){
        int col = n0 + wn + fn*16 + (lane & 15);
        int rb  = m0 + wm + fm*16 + (lane >> 4) * 4;
        float bv = bias[col];
        #pragma unroll
        for (int e = 0; e < 4; e++)
            out[(size_t)(rb + e) * HID + col] = acc[fm][fn][e] + bv;
    }
}

extern "C" void kernel_launch(void* const* d_in, const int* in_sizes, int n_in,
                              void* d_out, int out_size, void* d_ws, size_t ws_size,
                              hipStream_t stream)
{
    const float* q  = (const float*)d_in[0];
    const float* k  = (const float*)d_in[1];
    const float* v  = (const float*)d_in[2];
    const float* attn_bias = (const float*)d_in[3];
    const int*   attn_mask = (const int*)d_in[4];
    const float* Wq = (const float*)d_in[5];
    const float* bq = (const float*)d_in[6];
    const float* Wk = (const float*)d_in[7];
    const float* bk = (const float*)d_in[8];
    const float* Wv = (const float*)d_in[9];
    const float* bv = (const float*)d_in[10];
    const float* Wo = (const float*)d_in[11];
    const float* bo = (const float*)d_in[12];

    float* out = (float*)d_out;
    float* scores = out + (size_t)M * HID;   // output 1 region, also used as p_unnorm scratch

    char* p = (char*)d_ws;
    auto alloc = [&](size_t bytes){ char* r = p; p += (bytes + 255) & ~(size_t)255; return r; };
    const size_t PLANE  = (size_t)M * HID * 2;     // 4 MB bf16 plane
    const size_t WPLANE = (size_t)HID * HID * 2;   // 0.5 MB
    unsigned short* q_hi = (unsigned short*)alloc(PLANE);
    unsigned short* q_lo = (unsigned short*)alloc(PLANE);
    unsigned short* k_hi = (unsigned short*)alloc(PLANE);
    unsigned short* k_lo = (unsigned short*)alloc(PLANE);
    unsigned short* v_b  = (unsigned short*)alloc(PLANE);
    unsigned short* wqt_hi = (unsigned short*)alloc(WPLANE);
    unsigned short* wqt_lo = (unsigned short*)alloc(WPLANE);
    unsigned short* wkt_hi = (unsigned short*)alloc(WPLANE);
    unsigned short* wkt_lo = (unsigned short*)alloc(WPLANE);
    unsigned short* wvt    = (unsigned short*)alloc(WPLANE);
    unsigned short* wot    = (unsigned short*)alloc(WPLANE);
    unsigned short* qh_hi = (unsigned short*)alloc(PLANE);
    unsigned short* qh_lo = (unsigned short*)alloc(PLANE);
    unsigned short* kh_hi = (unsigned short*)alloc(PLANE);
    unsigned short* kh_lo = (unsigned short*)alloc(PLANE);
    unsigned short* vh_t  = (unsigned short*)alloc(PLANE);
    unsigned short* ctx   = (unsigned short*)alloc(PLANE);
    float* partials = (float*)alloc((size_t)SKB * NROWS * 4);
    float* invl     = (float*)alloc((size_t)NROWS * 4);
    if ((size_t)(p - (char*)d_ws) > ws_size) return;  // fail loudly if scratch too small

    const int n = M * HID;
    cvt_split<<<(n + 255) / 256, 256, 0, stream>>>(q, q_hi, q_lo, n);
    cvt_split<<<(n + 255) / 256, 256, 0, stream>>>(k, k_hi, k_lo, n);
    cvt_split<<<(n + 255) / 256, 256, 0, stream>>>(v, v_b, nullptr, n);
    dim3 wb(32, 8);
    cvt_w<<<dim3(16, 16), wb, 0, stream>>>(Wq, wqt_hi, wqt_lo);
    cvt_w<<<dim3(16, 16), wb, 0, stream>>>(Wk, wkt_hi, wkt_lo);
    cvt_w<<<dim3(16, 16), wb, 0, stream>>>(Wv, wvt, nullptr);
    cvt_w<<<dim3(16, 16), wb, 0, stream>>>(Wo, wot, nullptr);

    dim3 pg(HID / 64, M / 64);
    proj_gemm<1,0><<<pg, 256, 0, stream>>>(q_hi, q_lo, wqt_hi, wqt_lo, bq, qh_hi, qh_lo);
    proj_gemm<1,0><<<pg, 256, 0, stream>>>(k_hi, k_lo, wkt_hi, wkt_lo, bk, kh_hi, kh_lo);
    proj_gemm<0,1><<<pg, 256, 0, stream>>>(v_b, nullptr, wvt, nullptr, bv, vh_t, nullptr);

    scores_kernel<<<dim3(SKB, SEQ / 64, NB * NH), 256, 0, stream>>>(
        qh_hi, qh_lo, kh_hi, kh_lo, attn_bias, attn_mask, scores, partials);
    rowsum_inv<<<NROWS / 256, 256, 0, stream>>>(partials, invl);
    pv_kernel<<<dim3(SEQ / 64, NB * NH), 256, 0, stream>>>(scores, invl, vh_t, ctx);
    out_gemm<<<dim3(HID / 64, M / 64), 256, 0, stream>>>(ctx, wot, bo, out);
}

// Round 2
// 868.079 us; speedup vs baseline: 1.2262x; 1.2262x over previous
//
#include <hip/hip_runtime.h>
#include <hip/hip_bf16.h>

constexpr int HID = 512;
constexpr int NH  = 8;
constexpr int HD  = 64;
constexpr int NB  = 2;
constexpr int SEQ = 2048;
constexpr int M   = NB * SEQ;        // 4096 token rows
constexpr int NROWS = NB * NH * SEQ; // 32768 attention rows
constexpr int SKB = SEQ / 64;        // 32 sk blocks
constexpr int PVSPLIT = 2;           // pv sk-splits (partials fit in dead q/k planes)

typedef __attribute__((ext_vector_type(8))) short bf16x8;
typedef __attribute__((ext_vector_type(4))) float f32x4;

__device__ __forceinline__ unsigned short f2bf(float x){
    union { float f; unsigned u; } v; v.f = x;
    return (unsigned short)((v.u + 0x7fffu + ((v.u >> 16) & 1u)) >> 16);
}
__device__ __forceinline__ float bf2f(unsigned short h){
    union { unsigned u; float f; } v; v.u = (unsigned)h << 16;
    return v.f;
}

// ---------- input convert / split (hi+lo bf16 decomposition of fp32) ----------
__global__ void cvt_split(const float* __restrict__ x, unsigned short* __restrict__ hi,
                          unsigned short* __restrict__ lo, int n){
    int i = blockIdx.x * 256 + threadIdx.x;
    if (i >= n) return;
    float f = x[i];
    unsigned short h = f2bf(f);
    hi[i] = h;
    if (lo) lo[i] = f2bf(f - bf2f(h));
}

// ---------- weight transpose (+optional split): wt[n][k] = w[k][n] ----------
__global__ void cvt_w(const float* __restrict__ w, unsigned short* __restrict__ hi,
                      unsigned short* __restrict__ lo){
    __shared__ float t[32][33];
    int n0 = blockIdx.x * 32, k0 = blockIdx.y * 32;
    int tx = threadIdx.x, ty = threadIdx.y;
    for (int r = ty; r < 32; r += 8)
        t[r][tx] = w[(size_t)(k0 + r) * HID + n0 + tx];
    __syncthreads();
    for (int r = ty; r < 32; r += 8){
        float f = t[tx][r];                       // element (k=k0+tx, n=n0+r)
        unsigned short hb = f2bf(f);
        size_t o = (size_t)(n0 + r) * HID + k0 + tx;
        hi[o] = hb;
        if (lo) lo[o] = f2bf(f - bf2f(hb));
    }
}

// ---------- projection GEMM: Y[4096,512] = X @ W + b, MFMA 16x16x32 bf16 ----------
template<int SPLIT, int VOUT>
__global__ __launch_bounds__(256) void proj_gemm(
    const unsigned short* __restrict__ Ahi, const unsigned short* __restrict__ Alo,
    const unsigned short* __restrict__ Bhi, const unsigned short* __restrict__ Blo,
    const float* __restrict__ bias,
    unsigned short* __restrict__ Ohi, unsigned short* __restrict__ Olo)
{
    __shared__ __align__(16) unsigned short As[SPLIT + 1][64][40];
    __shared__ __align__(16) unsigned short Bs[SPLIT + 1][64][40];
    const int m0 = blockIdx.y * 64, n0 = blockIdx.x * 64;
    const int tid = threadIdx.x, w = tid >> 6, lane = tid & 63;
    const int wm = (w >> 1) * 32, wn = (w & 1) * 32;
    const int srow = tid >> 2, sch = (tid & 3) * 8;
    f32x4 acc[2][2] = {};
    for (int k0 = 0; k0 < HID; k0 += 32){
        *(bf16x8*)&As[0][srow][sch] = *(const bf16x8*)(Ahi + (size_t)(m0 + srow) * HID + k0 + sch);
        *(bf16x8*)&Bs[0][srow][sch] = *(const bf16x8*)(Bhi + (size_t)(n0 + srow) * HID + k0 + sch);
        if (SPLIT){
            *(bf16x8*)&As[1][srow][sch] = *(const bf16x8*)(Alo + (size_t)(m0 + srow) * HID + k0 + sch);
            *(bf16x8*)&Bs[1][srow][sch] = *(const bf16x8*)(Blo + (size_t)(n0 + srow) * HID + k0 + sch);
        }
        __syncthreads();
        const int fr = lane & 15, kc = (lane >> 4) * 8;
        #pragma unroll
        for (int fm = 0; fm < 2; fm++)
        #pragma unroll
        for (int fn = 0; fn < 2; fn++){
            bf16x8 aH = *(bf16x8*)&As[0][wm + fm*16 + fr][kc];
            bf16x8 bH = *(bf16x8*)&Bs[0][wn + fn*16 + fr][kc];
            acc[fm][fn] = __builtin_amdgcn_mfma_f32_16x16x32_bf16(aH, bH, acc[fm][fn], 0, 0, 0);
            if (SPLIT){
                bf16x8 aL = *(bf16x8*)&As[1][wm + fm*16 + fr][kc];
                bf16x8 bL = *(bf16x8*)&Bs[1][wn + fn*16 + fr][kc];
                acc[fm][fn] = __builtin_amdgcn_mfma_f32_16x16x32_bf16(aL, bH, acc[fm][fn], 0, 0, 0);
                acc[fm][fn] = __builtin_amdgcn_mfma_f32_16x16x32_bf16(aH, bL, acc[fm][fn], 0, 0, 0);
            }
        }
        __syncthreads();
    }
    #pragma unroll
    for (int fm = 0; fm < 2; fm++)
    #pragma unroll
    for (int fn = 0; fn < 2; fn++){
        int col = n0 + wn + fn*16 + (lane & 15);
        int rb  = m0 + wm + fm*16 + (lane >> 4) * 4;
        float bv = bias[col];
        int h = col >> 6, d = col & 63;
        #pragma unroll
        for (int e = 0; e < 4; e++){
            int m = rb + e;
            int b = m >> 11, s = m & (SEQ - 1);
            float y = acc[fm][fn][e] + bv;
            if (VOUT){
                Ohi[((size_t)((b * NH + h) * HD + d)) * SEQ + s] = f2bf(y);
            } else {
                size_t o = ((size_t)((b * NH + h) * SEQ + s)) * HD + d;
                unsigned short hb = f2bf(y);
                Ohi[o] = hb;
                if (SPLIT) Olo[o] = f2bf(y - bf2f(hb));
            }
        }
    }
}

// ---------- scores: p_unnorm = exp(QK^T*scale + bias, masked), + row partial sums ----------
// grid (bh=16, skb=32, sqb=32); LDS: staging unioned with fp32 x-tile -> 4 blocks/CU.
__global__ __launch_bounds__(256) void scores_kernel(
    const unsigned short* __restrict__ qh_hi, const unsigned short* __restrict__ qh_lo,
    const unsigned short* __restrict__ kh_hi, const unsigned short* __restrict__ kh_lo,
    const float* __restrict__ attn_bias, const int* __restrict__ attn_mask,
    float* __restrict__ scores, float* __restrict__ partials)
{
    __shared__ union {
        struct { unsigned short Aq[2][64][72]; unsigned short Bk[2][64][72]; } s; // 36864 B
        float Pt[64][68];                                                         // 17408 B
    } u;
    __shared__ float rs[64][4];
    const int bh = blockIdx.x, sk0 = blockIdx.y * 64, sq0 = blockIdx.z * 64;
    const int b = bh >> 3;
    const int tid = threadIdx.x, w = tid >> 6, lane = tid & 63;
    const int wm = (w >> 1) * 32, wn = (w & 1) * 32;

    for (int idx = tid; idx < 512; idx += 256){
        int row = idx >> 3, ch = (idx & 7) * 8;
        size_t qo = ((size_t)bh * SEQ + sq0 + row) * HD + ch;
        size_t ko = ((size_t)bh * SEQ + sk0 + row) * HD + ch;
        *(bf16x8*)&u.s.Aq[0][row][ch] = *(const bf16x8*)(qh_hi + qo);
        *(bf16x8*)&u.s.Aq[1][row][ch] = *(const bf16x8*)(qh_lo + qo);
        *(bf16x8*)&u.s.Bk[0][row][ch] = *(const bf16x8*)(kh_hi + ko);
        *(bf16x8*)&u.s.Bk[1][row][ch] = *(const bf16x8*)(kh_lo + ko);
    }
    __syncthreads();
    f32x4 acc[2][2] = {};
    const int fr = lane & 15, kc8 = (lane >> 4) * 8;
    #pragma unroll
    for (int ks = 0; ks < 2; ks++){
        int kc = ks * 32 + kc8;
        #pragma unroll
        for (int fm = 0; fm < 2; fm++)
        #pragma unroll
        for (int fn = 0; fn < 2; fn++){
            bf16x8 aH = *(bf16x8*)&u.s.Aq[0][wm + fm*16 + fr][kc];
            bf16x8 aL = *(bf16x8*)&u.s.Aq[1][wm + fm*16 + fr][kc];
            bf16x8 bH = *(bf16x8*)&u.s.Bk[0][wn + fn*16 + fr][kc];
            bf16x8 bL = *(bf16x8*)&u.s.Bk[1][wn + fn*16 + fr][kc];
            acc[fm][fn] = __builtin_amdgcn_mfma_f32_16x16x32_bf16(aH, bH, acc[fm][fn], 0, 0, 0);
            acc[fm][fn] = __builtin_amdgcn_mfma_f32_16x16x32_bf16(aL, bH, acc[fm][fn], 0, 0, 0);
            acc[fm][fn] = __builtin_amdgcn_mfma_f32_16x16x32_bf16(aH, bL, acc[fm][fn], 0, 0, 0);
        }
    }
    __syncthreads();   // all waves done reading Aq/Bk — safe to overwrite with Pt
    #pragma unroll
    for (int fm = 0; fm < 2; fm++)
    #pragma unroll
    for (int fn = 0; fn < 2; fn++){
        int c  = wn + fn*16 + (lane & 15);
        int rb = wm + fm*16 + (lane >> 4) * 4;
        #pragma unroll
        for (int e = 0; e < 4; e++)
            u.Pt[rb + e][c] = acc[fm][fn][e] * 0.125f;
    }
    __syncthreads();
    // streaming phase: thread -> row r = tid>>2, 16 contiguous cols at q*16
    {
        const int r = tid >> 2, qq = tid & 3;
        const size_t rowoff = ((size_t)bh * SEQ + sq0 + r) * SEQ + sk0 + qq * 16;
        const float* brow = attn_bias + rowoff;
        const int*   mrow = attn_mask + ((size_t)(b * SEQ + sq0 + r)) * SEQ + sk0 + qq * 16;
        float*       srow = scores + rowoff;
        float sum = 0.f;
        #pragma unroll
        for (int j = 0; j < 4; j++){
            float4 bi = *(const float4*)(brow + j * 4);
            int4   mk = *(const int4*)(mrow + j * 4);
            float4 xv = *(const float4*)&u.Pt[r][qq * 16 + j * 4];
            float4 pv;
            pv.x = mk.x ? 0.f : __expf(xv.x + bi.x);
            pv.y = mk.y ? 0.f : __expf(xv.y + bi.y);
            pv.z = mk.z ? 0.f : __expf(xv.z + bi.z);
            pv.w = mk.w ? 0.f : __expf(xv.w + bi.w);
            *(float4*)(srow + j * 4) = pv;
            sum += pv.x + pv.y + pv.z + pv.w;
        }
        rs[r][qq] = sum;
    }
    __syncthreads();
    if (tid < 64){
        float s = rs[tid][0] + rs[tid][1] + rs[tid][2] + rs[tid][3];
        partials[(size_t)blockIdx.y * NROWS + (size_t)bh * SEQ + sq0 + tid] = s;
    }
}

// ---------- reduce partial sums -> 1/l ----------
__global__ void rowsum_inv(const float* __restrict__ partials, float* __restrict__ invl){
    int r = blockIdx.x * 256 + threadIdx.x;
    float s = 0.f;
    for (int j = 0; j < SKB; j++) s += partials[(size_t)j * NROWS + r];
    invl[r] = 1.0f / s;
}

// ---------- normalize scores in place + ctx partials = P @ V (sk-split) ----------
__global__ __launch_bounds__(256) void pv_kernel(
    float* __restrict__ scores, const float* __restrict__ invl,
    const unsigned short* __restrict__ vh_t, float* __restrict__ ctx_part)
{
    __shared__ __align__(16) unsigned short Ap[64][72];
    __shared__ __align__(16) unsigned short Bv[64][72];
    __shared__ float il[64];
    const int sq0 = blockIdx.x * 64, bh = blockIdx.y, sp = blockIdx.z;
    const int tid = threadIdx.x, w = tid >> 6, lane = tid & 63;
    const int wm = (w >> 1) * 32, wn = (w & 1) * 32;
    if (tid < 64) il[tid] = invl[(size_t)bh * SEQ + sq0 + tid];
    __syncthreads();
    f32x4 acc[2][2] = {};
    const int skbeg = sp * (SEQ / PVSPLIT), skend = skbeg + SEQ / PVSPLIT;
    for (int sk0 = skbeg; sk0 < skend; sk0 += 64){
        for (int idx = tid; idx < 1024; idx += 256){
            int row = idx >> 4, c4 = (idx & 15) * 4;
            size_t o = ((size_t)bh * SEQ + sq0 + row) * SEQ + sk0 + c4;
            float4 pv = *(float4*)(scores + o);
            float sc = il[row];
            pv.x *= sc; pv.y *= sc; pv.z *= sc; pv.w *= sc;
            *(float4*)(scores + o) = pv;       // final normalized scores output
            ushort4 u; u.x = f2bf(pv.x); u.y = f2bf(pv.y); u.z = f2bf(pv.z); u.w = f2bf(pv.w);
            *(ushort4*)&Ap[row][c4] = u;
        }
        for (int idx = tid; idx < 512; idx += 256){
            int row = idx >> 3, ch = (idx & 7) * 8;
            *(bf16x8*)&Bv[row][ch] = *(const bf16x8*)(vh_t + ((size_t)bh * HD + row) * SEQ + sk0 + ch);
        }
        __syncthreads();
        const int fr = lane & 15, kc8 = (lane >> 4) * 8;
        #pragma unroll
        for (int ks = 0; ks < 2; ks++){
            int kc = ks * 32 + kc8;
            #pragma unroll
            for (int fm = 0; fm < 2; fm++)
            #pragma unroll
            for (int fn = 0; fn < 2; fn++){
                bf16x8 a  = *(bf16x8*)&Ap[wm + fm*16 + fr][kc];
                bf16x8 bb = *(bf16x8*)&Bv[wn + fn*16 + fr][kc];
                acc[fm][fn] = __builtin_amdgcn_mfma_f32_16x16x32_bf16(a, bb, acc[fm][fn], 0, 0, 0);
            }
        }
        __syncthreads();
    }
    // write fp32 partial ctx [sp][bh*SEQ+sq][d]
    #pragma unroll
    for (int fm = 0; fm < 2; fm++)
    #pragma unroll
    for (int fn = 0; fn < 2; fn++){
        int c  = wn + fn*16 + (lane & 15);
        int rb = wm + fm*16 + (lane >> 4) * 4;
        #pragma unroll
        for (int e = 0; e < 4; e++)
            ctx_part[((size_t)sp * NROWS + (size_t)bh * SEQ + sq0 + rb + e) * HD + c] = acc[fm][fn][e];
    }
}

// ---------- sum ctx partials, convert to bf16 [b,s,h*64+d] ----------
__global__ void ctx_reduce(const float* __restrict__ part, unsigned short* __restrict__ ctx){
    int i = blockIdx.x * 256 + threadIdx.x;       // over NROWS*HD
    float s = 0.f;
    #pragma unroll
    for (int sp = 0; sp < PVSPLIT; sp++) s += part[(size_t)sp * NROWS * HD + i];
    int m = i >> 6, d = i & 63;                   // m = bh*SEQ + s_
    int bhv = m >> 11, s_ = m & (SEQ - 1);
    int b = bhv >> 3, h = bhv & 7;
    ctx[((size_t)(b * SEQ + s_)) * HID + h * HD + d] = f2bf(s);
}

// ---------- out = ctx @ Wo + bo (fp32 out) ----------
__global__ __launch_bounds__(256) void out_gemm(
    const unsigned short* __restrict__ A, const unsigned short* __restrict__ Bt,
    const float* __restrict__ bias, float* __restrict__ out)
{
    __shared__ __align__(16) unsigned short As[64][40];
    __shared__ __align__(16) unsigned short Bs[64][40];
    const int m0 = blockIdx.y * 64, n0 = blockIdx.x * 64;
    const int tid = threadIdx.x, w = tid >> 6, lane = tid & 63;
    const int wm = (w >> 1) * 32, wn = (w & 1) * 32;
    const int srow = tid >> 2, sch = (tid & 3) * 8;
    f32x4 acc[2][2] = {};
    for (int k0 = 0; k0 < HID; k0 += 32){
        *(bf16x8*)&As[srow][sch] = *(const bf16x8*)(A  + (size_t)(m0 + srow) * HID + k0 + sch);
        *(bf16x8*)&Bs[srow][sch] = *(const bf16x8*)(Bt + (size_t)(n0 + srow) * HID + k0 + sch);
        __syncthreads();
        const int fr = lane & 15, kc = (lane >> 4) * 8;
        #pragma unroll
        for (int fm = 0; fm < 2; fm++)
        #pragma unroll
        for (int fn = 0; fn < 2; fn++){
            bf16x8 a = *(bf16x8*)&As[wm + fm*16 + fr][kc];
            bf16x8 b = *(bf16x8*)&Bs[wn + fn*16 + fr][kc];
            acc[fm][fn] = __builtin_amdgcn_mfma_f32_16x16x32_bf16(a, b, acc[fm][fn], 0, 0, 0);
        }
        __syncthreads();
    }
    #pragma unroll
    for (int fm = 0; fm < 2; fm++)
    #pragma unroll
    for (int fn = 0; fn < 2; fn++){
        int col = n0 + wn + fn*16 + (lane & 15);
        int rb  = m0 + wm + fm*16 + (lane >> 4) * 4;
        float bv = bias[col];
        #pragma unroll
        for (int e = 0; e < 4; e++)
            out[(size_t)(rb + e) * HID + col] = acc[fm][fn][e] + bv;
    }
}

extern "C" void kernel_launch(void* const* d_in, const int* in_sizes, int n_in,
                              void* d_out, int out_size, void* d_ws, size_t ws_size,
                              hipStream_t stream)
{
    const float* q  = (const float*)d_in[0];
    const float* k  = (const float*)d_in[1];
    const float* v  = (const float*)d_in[2];
    const float* attn_bias = (const float*)d_in[3];
    const int*   attn_mask = (const int*)d_in[4];
    const float* Wq = (const float*)d_in[5];
    const float* bq = (const float*)d_in[6];
    const float* Wk = (const float*)d_in[7];
    const float* bk = (const float*)d_in[8];
    const float* Wv = (const float*)d_in[9];
    const float* bv = (const float*)d_in[10];
    const float* Wo = (const float*)d_in[11];
    const float* bo = (const float*)d_in[12];

    float* out = (float*)d_out;
    float* scores = out + (size_t)M * HID;   // output 1 region, also used as p_unnorm scratch

    char* p = (char*)d_ws;
    auto alloc = [&](size_t bytes){ char* r = p; p += (bytes + 255) & ~(size_t)255; return r; };
    const size_t PLANE  = (size_t)M * HID * 2;     // 4 MB bf16 plane
    const size_t WPLANE = (size_t)HID * HID * 2;   // 0.5 MB
    unsigned short* q_hi = (unsigned short*)alloc(PLANE);
    unsigned short* q_lo = (unsigned short*)alloc(PLANE);
    unsigned short* k_hi = (unsigned short*)alloc(PLANE);
    unsigned short* k_lo = (unsigned short*)alloc(PLANE);
    unsigned short* v_b  = (unsigned short*)alloc(PLANE);
    unsigned short* wqt_hi = (unsigned short*)alloc(WPLANE);
    unsigned short* wqt_lo = (unsigned short*)alloc(WPLANE);
    unsigned short* wkt_hi = (unsigned short*)alloc(WPLANE);
    unsigned short* wkt_lo = (unsigned short*)alloc(WPLANE);
    unsigned short* wvt    = (unsigned short*)alloc(WPLANE);
    unsigned short* wot    = (unsigned short*)alloc(WPLANE);
    unsigned short* qh_hi = (unsigned short*)alloc(PLANE);
    unsigned short* qh_lo = (unsigned short*)alloc(PLANE);
    unsigned short* kh_hi = (unsigned short*)alloc(PLANE);
    unsigned short* kh_lo = (unsigned short*)alloc(PLANE);
    unsigned short* vh_t  = (unsigned short*)alloc(PLANE);
    unsigned short* ctx   = (unsigned short*)alloc(PLANE);
    float* partials = (float*)alloc((size_t)SKB * NROWS * 4);
    float* invl     = (float*)alloc((size_t)NROWS * 4);
    if ((size_t)(p - (char*)d_ws) > ws_size) return;
    // ctx partials overlay the q/k split planes (dead after the 3 proj_gemms):
    // need PVSPLIT * NROWS * HD * 4 = 16.8 MB <= q_hi..v_b (20 MB contiguous).
    float* ctx_part = (float*)q_hi;

    const int n = M * HID;
    cvt_split<<<(n + 255) / 256, 256, 0, stream>>>(q, q_hi, q_lo, n);
    cvt_split<<<(n + 255) / 256, 256, 0, stream>>>(k, k_hi, k_lo, n);
    cvt_split<<<(n + 255) / 256, 256, 0, stream>>>(v, v_b, nullptr, n);
    dim3 wb(32, 8);
    cvt_w<<<dim3(16, 16), wb, 0, stream>>>(Wq, wqt_hi, wqt_lo);
    cvt_w<<<dim3(16, 16), wb, 0, stream>>>(Wk, wkt_hi, wkt_lo);
    cvt_w<<<dim3(16, 16), wb, 0, stream>>>(Wv, wvt, nullptr);
    cvt_w<<<dim3(16, 16), wb, 0, stream>>>(Wo, wot, nullptr);

    dim3 pg(HID / 64, M / 64);
    proj_gemm<1,0><<<pg, 256, 0, stream>>>(q_hi, q_lo, wqt_hi, wqt_lo, bq, qh_hi, qh_lo);
    proj_gemm<1,0><<<pg, 256, 0, stream>>>(k_hi, k_lo, wkt_hi, wkt_lo, bk, kh_hi, kh_lo);
    proj_gemm<0,1><<<pg, 256, 0, stream>>>(v_b, nullptr, wvt, nullptr, bv, vh_t, nullptr);

    scores_kernel<<<dim3(NB * NH, SKB, SEQ / 64), 256, 0, stream>>>(
        qh_hi, qh_lo, kh_hi, kh_lo, attn_bias, attn_mask, scores, partials);
    rowsum_inv<<<NROWS / 256, 256, 0, stream>>>(partials, invl);
    pv_kernel<<<dim3(SEQ / 64, NB * NH, PVSPLIT), 256, 0, stream>>>(scores, invl, vh_t, ctx_part);
    ctx_reduce<<<(NROWS * HD) / 256, 256, 0, stream>>>(ctx_part, ctx);
    out_gemm<<<dim3(HID / 64, M / 64), 256, 0, stream>>>(ctx, wot, bo, out);
}